// Round 4
// baseline (1869.713 us; speedup 1.0000x reference)
//
#include <hip/hip_runtime.h>
#include <hip/hip_bf16.h>
#include <math.h>

// Problem constants
// B=64, H=W=56, C=192, NH=6, WS=7, SS=3, N=49, HD=32, MLP_H=768
// M (rows through all GEMMs) = B*H*W = 200704 = 1568*128 = 3136*64
// ALL inputs / output are FP32 (per reference dtypes). Internally: bf16 MFMA.

typedef __attribute__((ext_vector_type(8))) short short8;
typedef __attribute__((ext_vector_type(4))) short short4v;
typedef __attribute__((ext_vector_type(4))) float floatx4;

static __device__ __forceinline__ float bf2f(__hip_bfloat16 v) { return __bfloat162float(v); }

static __device__ __forceinline__ short f2bs(float f) {
    union { __hip_bfloat16 h; short s; } u;
    u.h = __float2bfloat16(f);
    return u.s;
}

// ---------------------------------------------------------------------------
// Convert weights fp32 -> bf16.
// qkv_w, proj_w: linear row-major (for gemm_bt).
// fc1_w -> w1f FRAGMENT layout: [c 0..47][ks 0..5][lane 0..63][8]
//   element = fc1_w[(c*16 + (lane&15))*192 + ks*32 + (lane>>4)*8 + j]
//   => per kg (2 c's) the w1 slab is 12KB CONTIGUOUS at kg*12KB.
// fc2_w -> w2f FRAGMENT layout: [kg 0..23][ct 0..11][lane 0..63][8]
//   element = fc2_w[(ct*16 + (lane&15))*768 + kg*32 + (lane>>4)*8 + j]
//   => per kg the w2 slab is 12KB CONTIGUOUS at kg*12KB.
// ---------------------------------------------------------------------------
__global__ __launch_bounds__(256)
void cvt_w(const float* __restrict__ a, const float* __restrict__ b,
           const float* __restrict__ c, const float* __restrict__ d,
           __hip_bfloat16* __restrict__ o)
{
    int i = blockIdx.x * 256 + threadIdx.x;
    float v;
    if (i < 110592)      v = a[i];
    else if (i < 147456) v = b[i - 110592];
    else if (i < 294912) {
        int l = i - 147456;
        int j = l & 7, ln = (l >> 3) & 63, t = l >> 9;
        int ks = t % 6, cc = t / 6;
        v = c[(cc * 16 + (ln & 15)) * 192 + ks * 32 + (ln >> 4) * 8 + j];
    } else {
        int l = i - 294912;
        int j = l & 7, ln = (l >> 3) & 63, t = l >> 9;   // t = kg*12 + ct
        int ct = t % 12, kg = t / 12;
        v = d[(ct * 16 + (ln & 15)) * 768 + kg * 32 + (ln >> 4) * 8 + j];
    }
    o[i] = __float2bfloat16(v);
}

// ---------------------------------------------------------------------------
// LN1 + cyclic shift (-3,-3) + window partition. One wave per row.
// ---------------------------------------------------------------------------
__global__ __launch_bounds__(256)
void ln1_shift_win(const float* __restrict__ x,
                   const float* __restrict__ g,
                   const float* __restrict__ bt,
                   __hip_bfloat16* __restrict__ yw)
{
    int r = blockIdx.x * 4 + (threadIdx.x >> 6);
    int lane = threadIdx.x & 63;
    int win = r / 49, t = r - win * 49;
    int b = win >> 6, wi = win & 63;
    int wh = wi >> 3, ww = wi & 7;
    int tr = t / 7, tc = t - tr * 7;
    int hs = wh * 7 + tr + 3; if (hs >= 56) hs -= 56;
    int ws = ww * 7 + tc + 3; if (ws >= 56) ws -= 56;
    const float* src = x + ((size_t)b * 3136 + hs * 56 + ws) * 192;
    float v0 = src[lane];
    float v1 = src[lane + 64];
    float v2 = src[lane + 128];
    float s  = v0 + v1 + v2;
    float s2 = v0 * v0 + v1 * v1 + v2 * v2;
#pragma unroll
    for (int off = 32; off; off >>= 1) { s += __shfl_xor(s, off); s2 += __shfl_xor(s2, off); }
    float mean = s * (1.0f / 192.0f);
    float var  = s2 * (1.0f / 192.0f) - mean * mean;
    float rstd = rsqrtf(var + 1e-5f);
    __hip_bfloat16* dst = yw + (size_t)r * 192;
    dst[lane]       = __float2bfloat16((v0 - mean) * rstd * g[lane]       + bt[lane]);
    dst[lane + 64]  = __float2bfloat16((v1 - mean) * rstd * g[lane + 64]  + bt[lane + 64]);
    dst[lane + 128] = __float2bfloat16((v2 - mean) * rstd * g[lane + 128] + bt[lane + 128]);
}

// ---------------------------------------------------------------------------
// Precompute bias+mask table in MFMA fragment layout.
// ---------------------------------------------------------------------------
__global__ __launch_bounds__(256)
void build_tbl(const float* __restrict__ rpb, float* __restrict__ tbl)
{
    int bid = blockIdx.x;          // head*4 + cls, 24 blocks
    int head = bid >> 2, cls = bid & 3;
    int ch = cls >> 1, cw = cls & 1;
    for (int idx = threadIdx.x; idx < 4096; idx += 256) {
        int tile = idx >> 8, lane = (idx >> 2) & 63, rg = idx & 3;
        int mt = tile >> 2, nt = tile & 3;
        int lm = lane & 15, quad = lane >> 4;
        int i = nt * 16 + lm;              // q token
        int j = mt * 16 + quad * 4 + rg;   // k token
        float v;
        if (i >= 49 || j >= 49) {
            v = -1e30f;
        } else {
            int ri = i / 7, ci = i - ri * 7;
            int rj = j / 7, cj = j - rj * 7;
            int bidx = (ri - rj + 6) * 13 + (ci - cj + 6);
            v = rpb[bidx * 6 + head];
            int rio = ch ? (ri < 4 ? 1 : 2) : 0;
            int cio = cw ? (ci < 4 ? 1 : 2) : 0;
            int rjo = ch ? (rj < 4 ? 1 : 2) : 0;
            int cjo = cw ? (cj < 4 ? 1 : 2) : 0;
            if (rio * 3 + cio != rjo * 3 + cjo) v -= 100.0f;
        }
        tbl[(size_t)bid * 4096 + idx] = v;
    }
}

// ---------------------------------------------------------------------------
// MFMA attention: one WAVE per (window, head); 4 waves/block, no barriers.
// ---------------------------------------------------------------------------
__global__ __launch_bounds__(256)
void attn_mfma(const __hip_bfloat16* __restrict__ qkv,
               const float* __restrict__ tbl,
               const float* __restrict__ gate,
               __hip_bfloat16* __restrict__ o)
{
    __shared__ __align__(16) char lds[49152];
    const int wave = threadIdx.x >> 6, lane = threadIdx.x & 63;
    const int lm = lane & 15, quad = lane >> 4;
    const int idx = blockIdx.x * 4 + wave;
    const int win = idx / 6;
    const int head = idx - win * 6;
    const int wi = win & 63;
    const int cls = (((wi >> 3) == 7) ? 2 : 0) + (((wi & 7) == 7) ? 1 : 0);

    char* vTb = lds + wave * 12288;   // [32][64] bf16, swizzled
    char* Pb  = vTb + 4096;           // [64][64] bf16, swizzled

    const __hip_bfloat16* base = qkv + (size_t)win * 49 * 576 + head * 32;

    // ---- stage V^T (lane = token t; zero-fill t>=49) ----
    {
        short8 v0 = {0,0,0,0,0,0,0,0}, v1 = {0,0,0,0,0,0,0,0};
        short8 v2 = {0,0,0,0,0,0,0,0}, v3 = {0,0,0,0,0,0,0,0};
        if (lane < 49) {
            const short* p = (const short*)(base + 384) + (size_t)lane * 576;
            v0 = *(const short8*)(p);
            v1 = *(const short8*)(p + 8);
            v2 = *(const short8*)(p + 16);
            v3 = *(const short8*)(p + 24);
        }
#pragma unroll
        for (int d = 0; d < 32; ++d) {
            short val = (d < 8) ? v0[d & 7] : (d < 16) ? v1[d & 7] : (d < 24) ? v2[d & 7] : v3[d & 7];
            *(short*)(vTb + ((d * 128 + lane * 2) ^ ((d & 7) << 4))) = val;
        }
    }

    // ---- load Q,K fragments ----
    short8 qf[4], kf[4];
    const short* qsrc = (const short*)base + quad * 8;
    const short* ksrc = (const short*)(base + 192) + quad * 8;
#pragma unroll
    for (int tt = 0; tt < 4; ++tt) {
        int t = tt * 16 + lm;
        if (t < 49) {
            qf[tt] = *(const short8*)(qsrc + (size_t)t * 576);
            kf[tt] = *(const short8*)(ksrc + (size_t)t * 576);
        } else {
            qf[tt] = (short8){0,0,0,0,0,0,0,0};
            kf[tt] = (short8){0,0,0,0,0,0,0,0};
        }
    }

    // ---- S^T = K @ Q^T ----
    const floatx4 z4 = {0.f, 0.f, 0.f, 0.f};
    floatx4 s[4][4];
#pragma unroll
    for (int mt = 0; mt < 4; ++mt)
#pragma unroll
        for (int nt = 0; nt < 4; ++nt)
            s[mt][nt] = __builtin_amdgcn_mfma_f32_16x16x32_bf16(kf[mt], qf[nt], z4, 0, 0, 0);

    // ---- scale + bias/mask/pad table ----
    const float* tb = tbl + (size_t)(head * 4 + cls) * 4096 + lane * 4;
#pragma unroll
    for (int mt = 0; mt < 4; ++mt)
#pragma unroll
        for (int nt = 0; nt < 4; ++nt) {
            floatx4 b = *(const floatx4*)(tb + (mt * 4 + nt) * 256);
#pragma unroll
            for (int rg = 0; rg < 4; ++rg)
                s[mt][nt][rg] = s[mt][nt][rg] * 0.17677669529663689f + b[rg];
        }

    const float gt = 1.0f / (1.0f + __expf(-gate[head]));

    // ---- softmax over k ----
    float inv[4];
#pragma unroll
    for (int nt = 0; nt < 4; ++nt) {
        float mx = -1e30f;
#pragma unroll
        for (int mt = 0; mt < 4; ++mt)
#pragma unroll
            for (int rg = 0; rg < 4; ++rg) mx = fmaxf(mx, s[mt][nt][rg]);
        mx = fmaxf(mx, __shfl_xor(mx, 16));
        mx = fmaxf(mx, __shfl_xor(mx, 32));
        float sum = 0.f;
#pragma unroll
        for (int mt = 0; mt < 4; ++mt)
#pragma unroll
            for (int rg = 0; rg < 4; ++rg) {
                float e = __expf(s[mt][nt][rg] - mx);
                s[mt][nt][rg] = e;
                sum += e;
            }
        sum += __shfl_xor(sum, 16);
        sum += __shfl_xor(sum, 32);
        inv[nt] = gt / sum;
    }

    // ---- pack P -> bf16, swizzled LDS ----
#pragma unroll
    for (int nt = 0; nt < 4; ++nt) {
        int row = nt * 16 + lm;
#pragma unroll
        for (int mt = 0; mt < 4; ++mt) {
            short4v pk = { f2bs(s[mt][nt][0] * inv[nt]), f2bs(s[mt][nt][1] * inv[nt]),
                           f2bs(s[mt][nt][2] * inv[nt]), f2bs(s[mt][nt][3] * inv[nt]) };
            int off = (row * 128 + mt * 32 + quad * 8) ^ ((row & 7) << 4);
            *(short4v*)(Pb + off) = pk;
        }
    }

    // ---- O = P @ V ----
    floatx4 oacc[4][2];
#pragma unroll
    for (int pt = 0; pt < 4; ++pt)
#pragma unroll
        for (int nt = 0; nt < 2; ++nt) oacc[pt][nt] = z4;

#pragma unroll
    for (int ks = 0; ks < 2; ++ks) {
        short8 vfr[2];
#pragma unroll
        for (int nt = 0; nt < 2; ++nt) {
            int row = nt * 16 + lm;
            vfr[nt] = *(const short8*)(vTb + ((row * 128 + ks * 64 + quad * 16) ^ ((row & 7) << 4)));
        }
#pragma unroll
        for (int pt = 0; pt < 4; ++pt) {
            int row = pt * 16 + lm;
            short8 pfr = *(const short8*)(Pb + ((row * 128 + ks * 64 + quad * 16) ^ ((row & 7) << 4)));
#pragma unroll
            for (int nt = 0; nt < 2; ++nt)
                oacc[pt][nt] = __builtin_amdgcn_mfma_f32_16x16x32_bf16(pfr, vfr[nt], oacc[pt][nt], 0, 0, 0);
        }
    }

    // ---- store O ----
    __hip_bfloat16* obase = o + (size_t)win * 49 * 192 + head * 32;
#pragma unroll
    for (int pt = 0; pt < 4; ++pt) {
#pragma unroll
        for (int rg = 0; rg < 4; ++rg) {
            int q = pt * 16 + quad * 4 + rg;
            if (q < 49) {
#pragma unroll
                for (int nt = 0; nt < 2; ++nt)
                    obase[(size_t)q * 192 + nt * 16 + lm] = __float2bfloat16(oacc[pt][nt][rg]);
            }
        }
    }
}

// ---------------------------------------------------------------------------
// MFMA GEMM (qkv MODE 0, proj MODE 1).
// ---------------------------------------------------------------------------
template <int MODE>
__global__ __launch_bounds__(256, 2)
void gemm_bt(const __hip_bfloat16* __restrict__ A,
             const __hip_bfloat16* __restrict__ W,
             const float* __restrict__ bias,
             const float* __restrict__ ex0,
             void* __restrict__ OutV,
             int K, int Ncols)
{
    __shared__ __align__(16) char lds[(128 * 32 + 64 * 32) * 2];  // A: 8KB, B: 4KB
    short* sA = (short*)lds;
    short* sB = (short*)(lds + 8192);

    const int tid  = threadIdx.x;
    const int wave = tid >> 6, lane = tid & 63;
    const int m0 = blockIdx.x * 128;
    const int n0 = blockIdx.y * 64;
    const int wm = wave >> 1, wn = wave & 1;
    const int lm = lane & 15, quad = lane >> 4;

    floatx4 acc[4][2];
#pragma unroll
    for (int mt = 0; mt < 4; ++mt)
#pragma unroll
        for (int nt = 0; nt < 2; ++nt) acc[mt][nt] = (floatx4){0.f, 0.f, 0.f, 0.f};

    for (int kk = 0; kk < K; kk += 32) {
#pragma unroll
        for (int i = 0; i < 2; ++i) {
            int c = i * 256 + tid;
            int row = c >> 2, kc = c & 3;
            const __hip_bfloat16* gp = A + (size_t)(m0 + row) * K + kk + kc * 8;
            char* lp = lds + (i * 256 + wave * 64) * 16;
            __builtin_amdgcn_global_load_lds((const __attribute__((address_space(1))) void*)gp,
                                             (__attribute__((address_space(3))) void*)lp, 16, 0, 0);
        }
        {
            int c = tid;
            int row = c >> 2, kc = c & 3;
            const __hip_bfloat16* gp = W + (size_t)(n0 + row) * K + kk + kc * 8;
            char* lp = lds + 8192 + (wave * 64) * 16;
            __builtin_amdgcn_global_load_lds((const __attribute__((address_space(1))) void*)gp,
                                             (__attribute__((address_space(3))) void*)lp, 16, 0, 0);
        }
        asm volatile("s_waitcnt vmcnt(0)" ::: "memory");
        __syncthreads();

        short8 af[4], bf[2];
#pragma unroll
        for (int mt = 0; mt < 4; ++mt)
            af[mt] = *(const short8*)(sA + ((wm * 64 + mt * 16 + lm) * 32 + quad * 8));
#pragma unroll
        for (int nt = 0; nt < 2; ++nt)
            bf[nt] = *(const short8*)(sB + ((wn * 32 + nt * 16 + lm) * 32 + quad * 8));
#pragma unroll
        for (int mt = 0; mt < 4; ++mt)
#pragma unroll
            for (int nt = 0; nt < 2; ++nt)
                acc[mt][nt] = __builtin_amdgcn_mfma_f32_16x16x32_bf16(af[mt], bf[nt], acc[mt][nt], 0, 0, 0);
        __syncthreads();
    }

#pragma unroll
    for (int mt = 0; mt < 4; ++mt) {
#pragma unroll
        for (int nt = 0; nt < 2; ++nt) {
            int col = n0 + wn * 32 + nt * 16 + lm;
            float bcol = bias[col];
#pragma unroll
            for (int rg = 0; rg < 4; ++rg) {
                int row = m0 + wm * 64 + mt * 16 + quad * 4 + rg;
                float val = acc[mt][nt][rg] + bcol;
                if (MODE == 0) {
                    ((__hip_bfloat16*)OutV)[(size_t)row * Ncols + col] = __float2bfloat16(val);
                } else {  // MODE 1: proj + window reverse + unshift + residual
                    int win = row / 49, t = row - win * 49;
                    int b = win >> 6, wi = win & 63;
                    int wh = wi >> 3, ww = wi & 7;
                    int tr = t / 7, tc = t - tr * 7;
                    int h = wh * 7 + tr + 3; if (h >= 56) h -= 56;
                    int w = ww * 7 + tc + 3; if (w >= 56) w -= 56;
                    size_t dst = ((size_t)b * 3136 + h * 56 + w) * 192 + col;
                    ((float*)OutV)[dst] = val + ex0[dst];
                }
            }
        }
    }
}

// ---------------------------------------------------------------------------
// Fused MLP v3: barrier-light, register-resident.
// 128 tokens/block, 4 waves, each wave owns 32 tokens end-to-end.
// z (LN2 output) lives in REGISTERS (12 bf16 fragments/wave). Per k-group
// kg (24 x 32 h-cols): phase A = 12 LDS wf reads + 24 MFMA -> GELU in regs
// -> shfl-relayout (8 shfl + 4 selects per token-tile) into phase-B A-operand
// -> phase B = 12 LDS vf reads + 24 MFMA into persistent acc[2][12].
// Weights staged per-kg through double-buffered LDS (2 x 24KB) via
// global_load_lds from contiguous pre-packed slabs; ONE barrier per kg
// (buffer flip only -- waves never exchange data).
// ---------------------------------------------------------------------------
__global__ __launch_bounds__(256, 2)
void mlp_fused(float* __restrict__ xio,
               const __hip_bfloat16* __restrict__ w1f,
               const __hip_bfloat16* __restrict__ w2f,
               const float* __restrict__ fc1_b,
               const float* __restrict__ bn_g,
               const float* __restrict__ bn_b,
               const float* __restrict__ fc2_b,
               const float* __restrict__ n2g,
               const float* __restrict__ n2b)
{
    __shared__ __align__(16) char wlds[2][24576];   // per buf: w1 slab 12KB + w2 slab 12KB

    const int tid = threadIdx.x;
    const int wave = tid >> 6, lane = tid & 63;
    const int lm = lane & 15, quad = lane >> 4;
    const int t0 = blockIdx.x * 128 + wave * 32;

    // ---- phase 0: LN2 of this wave's 32 tokens -> z fragments in regs ----
    // zf[mt][ks]: lane (lm,quad) holds z[t0+mt*16+lm][ks*32+quad*8 .. +7]
    short8 zf[2][6];
    {
        floatx4 gg[6][2], bb[6][2];
#pragma unroll
        for (int ks = 0; ks < 6; ++ks) {
            gg[ks][0] = *(const floatx4*)(n2g + ks * 32 + quad * 8);
            gg[ks][1] = *(const floatx4*)(n2g + ks * 32 + quad * 8 + 4);
            bb[ks][0] = *(const floatx4*)(n2b + ks * 32 + quad * 8);
            bb[ks][1] = *(const floatx4*)(n2b + ks * 32 + quad * 8 + 4);
        }
#pragma unroll
        for (int mt = 0; mt < 2; ++mt) {
            const float* src = xio + (size_t)(t0 + mt * 16 + lm) * 192 + quad * 8;
            floatx4 v[6][2];
#pragma unroll
            for (int ks = 0; ks < 6; ++ks) {
                v[ks][0] = *(const floatx4*)(src + ks * 32);
                v[ks][1] = *(const floatx4*)(src + ks * 32 + 4);
            }
            float s = 0.f, s2 = 0.f;
#pragma unroll
            for (int ks = 0; ks < 6; ++ks)
#pragma unroll
                for (int h = 0; h < 2; ++h)
#pragma unroll
                    for (int r = 0; r < 4; ++r) { float x = v[ks][h][r]; s += x; s2 += x * x; }
            s  += __shfl_xor(s, 16);  s  += __shfl_xor(s, 32);
            s2 += __shfl_xor(s2, 16); s2 += __shfl_xor(s2, 32);
            float mean = s * (1.0f / 192.0f);
            float var  = s2 * (1.0f / 192.0f) - mean * mean;
            float rstd = rsqrtf(var + 1e-5f);
#pragma unroll
            for (int ks = 0; ks < 6; ++ks)
#pragma unroll
                for (int h = 0; h < 2; ++h)
#pragma unroll
                    for (int r = 0; r < 4; ++r) {
                        float nv = (v[ks][h][r] - mean) * rstd * gg[ks][h][r] + bb[ks][h][r];
                        zf[mt][ks][h * 4 + r] = f2bs(nv);
                    }
        }
    }

    floatx4 acc[2][12];
#pragma unroll
    for (int mt = 0; mt < 2; ++mt)
#pragma unroll
        for (int ct = 0; ct < 12; ++ct) acc[mt][ct] = (floatx4){0.f, 0.f, 0.f, 0.f};

    // ---- weight staging: kg slab = w1f[kg*12KB] (12KB) + w2f[kg*12KB] (12KB) ----
    auto stage = [&](int kg, int p) {
        const char* g1 = (const char*)w1f + (size_t)kg * 12288 + wave * 1024 + lane * 16;
        const char* g2 = (const char*)w2f + (size_t)kg * 12288 + wave * 1024 + lane * 16;
        char* l1 = &wlds[p][0] + wave * 1024;
        char* l2 = &wlds[p][0] + 12288 + wave * 1024;
#pragma unroll
        for (int i = 0; i < 3; ++i) {
            __builtin_amdgcn_global_load_lds((const __attribute__((address_space(1))) void*)(g1 + i * 4096),
                                             (__attribute__((address_space(3))) void*)(l1 + i * 4096), 16, 0, 0);
            __builtin_amdgcn_global_load_lds((const __attribute__((address_space(1))) void*)(g2 + i * 4096),
                                             (__attribute__((address_space(3))) void*)(l2 + i * 4096), 16, 0, 0);
        }
    };

    stage(0, 0);
    asm volatile("s_waitcnt vmcnt(0)" ::: "memory");
    __syncthreads();

    const int srcA = (quad & 1) * 32 + lm;
    const int srcB = srcA + 16;
    const int hi = quad >> 1;   // which h-col tile this lane's phase-B fragment needs

    int cur = 0;
    for (int kg = 0; kg < 24; ++kg) {
        if (kg < 23) stage(kg + 1, cur ^ 1);
        const char* sw1 = &wlds[cur][0];
        const char* sw2 = &wlds[cur][0] + 12288;

        // ---- phase A: aa[mt][u], token=t0+mt*16+lm, hcol=kg*32+u*16+quad*4+rg ----
        floatx4 aa[2][2];
#pragma unroll
        for (int mt = 0; mt < 2; ++mt)
#pragma unroll
            for (int u = 0; u < 2; ++u) aa[mt][u] = (floatx4){0.f, 0.f, 0.f, 0.f};
#pragma unroll
        for (int ks = 0; ks < 6; ++ks) {
            short8 wf0 = *(const short8*)(sw1 + ks * 1024 + lane * 16);
            short8 wf1 = *(const short8*)(sw1 + 6144 + ks * 1024 + lane * 16);
#pragma unroll
            for (int mt = 0; mt < 2; ++mt) {
                aa[mt][0] = __builtin_amdgcn_mfma_f32_16x16x32_bf16(wf0, zf[mt][ks], aa[mt][0], 0, 0, 0);
                aa[mt][1] = __builtin_amdgcn_mfma_f32_16x16x32_bf16(wf1, zf[mt][ks], aa[mt][1], 0, 0, 0);
            }
        }

        // ---- BN + GELU + pack; pw[mt][u][w] = packed bf16 pair (rg=2w, 2w+1) ----
        int pw[2][2][2];
#pragma unroll
        for (int u = 0; u < 2; ++u) {
            int colb = kg * 32 + u * 16 + quad * 4;
            floatx4 fb = *(const floatx4*)(fc1_b + colb);
            floatx4 G  = *(const floatx4*)(bn_g + colb);
            floatx4 Bb = *(const floatx4*)(bn_b + colb);
#pragma unroll
            for (int mt = 0; mt < 2; ++mt) {
                short hs[4];
#pragma unroll
                for (int rg = 0; rg < 4; ++rg) {
                    float t2 = (aa[mt][u][rg] + fb[rg]) * (G[rg] * 0.99999500003749968f) + Bb[rg];
                    float ge = 0.5f * t2 * (1.0f + erff(t2 * 0.70710678118654752f));
                    hs[rg] = f2bs(ge);
                }
                pw[mt][u][0] = (int)(unsigned short)hs[0] | ((int)(unsigned short)hs[1] << 16);
                pw[mt][u][1] = (int)(unsigned short)hs[2] | ((int)(unsigned short)hs[3] << 16);
            }
        }

        // ---- shfl-relayout into phase-B A-operand fragments ----
        // dest lane (lm,q) word i <- src lane (q&1)*32+lm + (i>>1)*16, word i&1, tile q>>1
        short8 hf[2];
#pragma unroll
        for (int mt = 0; mt < 2; ++mt) {
            int a0 = __shfl(pw[mt][0][0], srcA), a1 = __shfl(pw[mt][0][1], srcA);
            int a2 = __shfl(pw[mt][0][0], srcB), a3 = __shfl(pw[mt][0][1], srcB);
            int b0 = __shfl(pw[mt][1][0], srcA), b1 = __shfl(pw[mt][1][1], srcA);
            int b2 = __shfl(pw[mt][1][0], srcB), b3 = __shfl(pw[mt][1][1], srcB);
            union { int i[4]; short8 s; } u4;
            u4.i[0] = hi ? b0 : a0;
            u4.i[1] = hi ? b1 : a1;
            u4.i[2] = hi ? b2 : a2;
            u4.i[3] = hi ? b3 : a3;
            hf[mt] = u4.s;
        }

        // ---- phase B: acc[mt][ct] += hf[mt] @ w2[ct-tile, kg] ----
#pragma unroll 4
        for (int ct = 0; ct < 12; ++ct) {
            short8 vf = *(const short8*)(sw2 + ct * 1024 + lane * 16);
            acc[0][ct] = __builtin_amdgcn_mfma_f32_16x16x32_bf16(hf[0], vf, acc[0][ct], 0, 0, 0);
            acc[1][ct] = __builtin_amdgcn_mfma_f32_16x16x32_bf16(hf[1], vf, acc[1][ct], 0, 0, 0);
        }

        asm volatile("s_waitcnt vmcnt(0)" ::: "memory");
        __syncthreads();
        cur ^= 1;
    }

    // ---- epilogue: + fc2_b + x1 residual, fp32 store in place ----
    // acc: out-col = ct*16+lm, token = t0 + mt*16 + quad*4 + rg
#pragma unroll
    for (int ct = 0; ct < 12; ++ct) {
        float fb = fc2_b[ct * 16 + lm];
#pragma unroll
        for (int mt = 0; mt < 2; ++mt) {
#pragma unroll
            for (int rg = 0; rg < 4; ++rg) {
                size_t dst = (size_t)(t0 + mt * 16 + quad * 4 + rg) * 192 + ct * 16 + lm;
                xio[dst] = acc[mt][ct][rg] + fb + xio[dst];
            }
        }
    }
}

// ---------------------------------------------------------------------------
extern "C" void kernel_launch(void* const* d_in, const int* in_sizes, int n_in,
                              void* d_out, int out_size, void* d_ws, size_t ws_size,
                              hipStream_t stream)
{
    const float* x      = (const float*)d_in[0];
    const float* n1g    = (const float*)d_in[1];
    const float* n1b    = (const float*)d_in[2];
    const float* qkv_w  = (const float*)d_in[3];
    const float* qkv_b  = (const float*)d_in[4];
    const float* rpb    = (const float*)d_in[5];
    const float* gate   = (const float*)d_in[6];
    const float* proj_w = (const float*)d_in[7];
    const float* proj_b = (const float*)d_in[8];
    const float* n2g    = (const float*)d_in[9];
    const float* n2b    = (const float*)d_in[10];
    const float* fc1_w  = (const float*)d_in[11];
    const float* fc1_b  = (const float*)d_in[12];
    const float* bn_g   = (const float*)d_in[13];
    const float* bn_b   = (const float*)d_in[14];
    const float* fc2_w  = (const float*)d_in[15];
    const float* fc2_b  = (const float*)d_in[16];
    float* out = (float*)d_out;

    char* ws = (char*)d_ws;
    const int NCH = (ws_size >= 155025408u) ? 4 : 8;
    const size_t buf1max = (NCH == 4) ? 77070336u : 38535168u;
    __hip_bfloat16* buf0 = (__hip_bfloat16*)(ws);
    __hip_bfloat16* buf1 = (__hip_bfloat16*)(ws + 77070336);
    __hip_bfloat16* wbuf = (__hip_bfloat16*)(ws + 77070336 + buf1max);
    __hip_bfloat16* wq  = wbuf;            // 110592 (row-major)
    __hip_bfloat16* wp  = wbuf + 110592;   // 36864  (row-major)
    __hip_bfloat16* w1f = wbuf + 147456;   // 147456 (fragment layout, per-kg slabs)
    __hip_bfloat16* w2f = wbuf + 294912;   // 147456 (fragment layout, per-kg slabs)

    const int WINS = 4096 / NCH;        // windows per chunk (multiple of 64)
    const int ROWS = WINS * 49;         // rows per chunk
    const int GX   = ROWS / 128;        // gemm grid.x per chunk

    // attention bias table lives in buf1 AFTER the per-chunk qkv region.
    float* tbl = (float*)(ws + 77070336 + (size_t)ROWS * 576 * 2);

    // 0. Weights fp32 -> bf16 (w1/w2 into per-kg fragment slabs); bias+mask table
    cvt_w<<<dim3(1728), 256, 0, stream>>>(qkv_w, proj_w, fc1_w, fc2_w, wbuf);
    build_tbl<<<dim3(24), 256, 0, stream>>>(rpb, tbl);

    // 1. LN1 + shift + window partition (all rows)
    ln1_shift_win<<<dim3(200704 / 4), 256, 0, stream>>>(x, n1g, n1b, buf0);

    // 2+3. Per chunk: QKV gemm then MFMA attention
    for (int c = 0; c < NCH; ++c) {
        const __hip_bfloat16* ywc = buf0 + (size_t)c * ROWS * 192;
        __hip_bfloat16*       oc  = buf0 + (size_t)c * ROWS * 192;
        gemm_bt<0><<<dim3(GX, 9), 256, 0, stream>>>(ywc, wq, qkv_b, nullptr, buf1, 192, 576);
        attn_mfma<<<dim3(WINS * 6 / 4), 256, 0, stream>>>(buf1, tbl, gate, oc);
    }

    // 4. proj gemm + window reverse + unshift + shortcut -> x1 (fp32) in d_out
    gemm_bt<1><<<dim3(1568, 3), 256, 0, stream>>>(buf0, wp, proj_b, x, out, 192, 192);

    // 5. Fused LN2 + FC1 + BN + GELU + FC2 + residual (in-place on d_out)
    mlp_fused<<<dim3(1568), 256, 0, stream>>>(out, w1f, w2f, fc1_b, bn_g, bn_b, fc2_b, n2g, n2b);
}

// Round 5
// 852.992 us; speedup vs baseline: 2.1919x; 2.1919x over previous
//
#include <hip/hip_runtime.h>
#include <hip/hip_bf16.h>
#include <math.h>

// Problem constants
// B=64, H=W=56, C=192, NH=6, WS=7, SS=3, N=49, HD=32, MLP_H=768
// M (rows through all GEMMs) = B*H*W = 200704 = 1568*128 = 3136*64
// ALL inputs / output are FP32 (per reference dtypes). Internally: bf16 MFMA.

typedef __attribute__((ext_vector_type(8))) short short8;
typedef __attribute__((ext_vector_type(4))) short short4v;
typedef __attribute__((ext_vector_type(4))) float floatx4;

static __device__ __forceinline__ float bf2f(__hip_bfloat16 v) { return __bfloat162float(v); }

static __device__ __forceinline__ short f2bs(float f) {
    union { __hip_bfloat16 h; short s; } u;
    u.h = __float2bfloat16(f);
    return u.s;
}

// ---------------------------------------------------------------------------
// Convert weights fp32 -> bf16.
// qkv_w, proj_w: linear row-major (for gemm_bt).
// fc1_w -> w1f FRAGMENT layout: [c 0..47][ks 0..5][lane 0..63][8]
//   element = fc1_w[(c*16 + (lane&15))*192 + ks*32 + (lane>>4)*8 + j]
//   => per kg (2 c's) the w1 slab is 12KB CONTIGUOUS at kg*12KB.
// fc2_w -> w2f FRAGMENT layout: [kg 0..23][ct 0..11][lane 0..63][8]
//   element = fc2_w[(ct*16 + (lane&15))*768 + kg*32 + (lane>>4)*8 + j]
//   => per kg the w2 slab is 12KB CONTIGUOUS at kg*12KB.
// ---------------------------------------------------------------------------
__global__ __launch_bounds__(256)
void cvt_w(const float* __restrict__ a, const float* __restrict__ b,
           const float* __restrict__ c, const float* __restrict__ d,
           __hip_bfloat16* __restrict__ o)
{
    int i = blockIdx.x * 256 + threadIdx.x;
    float v;
    if (i < 110592)      v = a[i];
    else if (i < 147456) v = b[i - 110592];
    else if (i < 294912) {
        int l = i - 147456;
        int j = l & 7, ln = (l >> 3) & 63, t = l >> 9;
        int ks = t % 6, cc = t / 6;
        v = c[(cc * 16 + (ln & 15)) * 192 + ks * 32 + (ln >> 4) * 8 + j];
    } else {
        int l = i - 294912;
        int j = l & 7, ln = (l >> 3) & 63, t = l >> 9;   // t = kg*12 + ct
        int ct = t % 12, kg = t / 12;
        v = d[(ct * 16 + (ln & 15)) * 768 + kg * 32 + (ln >> 4) * 8 + j];
    }
    o[i] = __float2bfloat16(v);
}

// ---------------------------------------------------------------------------
// LN1 + cyclic shift (-3,-3) + window partition. One wave per row.
// ---------------------------------------------------------------------------
__global__ __launch_bounds__(256)
void ln1_shift_win(const float* __restrict__ x,
                   const float* __restrict__ g,
                   const float* __restrict__ bt,
                   __hip_bfloat16* __restrict__ yw)
{
    int r = blockIdx.x * 4 + (threadIdx.x >> 6);
    int lane = threadIdx.x & 63;
    int win = r / 49, t = r - win * 49;
    int b = win >> 6, wi = win & 63;
    int wh = wi >> 3, ww = wi & 7;
    int tr = t / 7, tc = t - tr * 7;
    int hs = wh * 7 + tr + 3; if (hs >= 56) hs -= 56;
    int ws = ww * 7 + tc + 3; if (ws >= 56) ws -= 56;
    const float* src = x + ((size_t)b * 3136 + hs * 56 + ws) * 192;
    float v0 = src[lane];
    float v1 = src[lane + 64];
    float v2 = src[lane + 128];
    float s  = v0 + v1 + v2;
    float s2 = v0 * v0 + v1 * v1 + v2 * v2;
#pragma unroll
    for (int off = 32; off; off >>= 1) { s += __shfl_xor(s, off); s2 += __shfl_xor(s2, off); }
    float mean = s * (1.0f / 192.0f);
    float var  = s2 * (1.0f / 192.0f) - mean * mean;
    float rstd = rsqrtf(var + 1e-5f);
    __hip_bfloat16* dst = yw + (size_t)r * 192;
    dst[lane]       = __float2bfloat16((v0 - mean) * rstd * g[lane]       + bt[lane]);
    dst[lane + 64]  = __float2bfloat16((v1 - mean) * rstd * g[lane + 64]  + bt[lane + 64]);
    dst[lane + 128] = __float2bfloat16((v2 - mean) * rstd * g[lane + 128] + bt[lane + 128]);
}

// ---------------------------------------------------------------------------
// Precompute bias+mask table in MFMA fragment layout.
// ---------------------------------------------------------------------------
__global__ __launch_bounds__(256)
void build_tbl(const float* __restrict__ rpb, float* __restrict__ tbl)
{
    int bid = blockIdx.x;          // head*4 + cls, 24 blocks
    int head = bid >> 2, cls = bid & 3;
    int ch = cls >> 1, cw = cls & 1;
    for (int idx = threadIdx.x; idx < 4096; idx += 256) {
        int tile = idx >> 8, lane = (idx >> 2) & 63, rg = idx & 3;
        int mt = tile >> 2, nt = tile & 3;
        int lm = lane & 15, quad = lane >> 4;
        int i = nt * 16 + lm;              // q token
        int j = mt * 16 + quad * 4 + rg;   // k token
        float v;
        if (i >= 49 || j >= 49) {
            v = -1e30f;
        } else {
            int ri = i / 7, ci = i - ri * 7;
            int rj = j / 7, cj = j - rj * 7;
            int bidx = (ri - rj + 6) * 13 + (ci - cj + 6);
            v = rpb[bidx * 6 + head];
            int rio = ch ? (ri < 4 ? 1 : 2) : 0;
            int cio = cw ? (ci < 4 ? 1 : 2) : 0;
            int rjo = ch ? (rj < 4 ? 1 : 2) : 0;
            int cjo = cw ? (cj < 4 ? 1 : 2) : 0;
            if (rio * 3 + cio != rjo * 3 + cjo) v -= 100.0f;
        }
        tbl[(size_t)bid * 4096 + idx] = v;
    }
}

// ---------------------------------------------------------------------------
// MFMA attention: one WAVE per (window, head); 4 waves/block, no barriers.
// ---------------------------------------------------------------------------
__global__ __launch_bounds__(256)
void attn_mfma(const __hip_bfloat16* __restrict__ qkv,
               const float* __restrict__ tbl,
               const float* __restrict__ gate,
               __hip_bfloat16* __restrict__ o)
{
    __shared__ __align__(16) char lds[49152];
    const int wave = threadIdx.x >> 6, lane = threadIdx.x & 63;
    const int lm = lane & 15, quad = lane >> 4;
    const int idx = blockIdx.x * 4 + wave;
    const int win = idx / 6;
    const int head = idx - win * 6;
    const int wi = win & 63;
    const int cls = (((wi >> 3) == 7) ? 2 : 0) + (((wi & 7) == 7) ? 1 : 0);

    char* vTb = lds + wave * 12288;   // [32][64] bf16, swizzled
    char* Pb  = vTb + 4096;           // [64][64] bf16, swizzled

    const __hip_bfloat16* base = qkv + (size_t)win * 49 * 576 + head * 32;

    // ---- stage V^T (lane = token t; zero-fill t>=49) ----
    {
        short8 v0 = {0,0,0,0,0,0,0,0}, v1 = {0,0,0,0,0,0,0,0};
        short8 v2 = {0,0,0,0,0,0,0,0}, v3 = {0,0,0,0,0,0,0,0};
        if (lane < 49) {
            const short* p = (const short*)(base + 384) + (size_t)lane * 576;
            v0 = *(const short8*)(p);
            v1 = *(const short8*)(p + 8);
            v2 = *(const short8*)(p + 16);
            v3 = *(const short8*)(p + 24);
        }
#pragma unroll
        for (int d = 0; d < 32; ++d) {
            short val = (d < 8) ? v0[d & 7] : (d < 16) ? v1[d & 7] : (d < 24) ? v2[d & 7] : v3[d & 7];
            *(short*)(vTb + ((d * 128 + lane * 2) ^ ((d & 7) << 4))) = val;
        }
    }

    // ---- load Q,K fragments ----
    short8 qf[4], kf[4];
    const short* qsrc = (const short*)base + quad * 8;
    const short* ksrc = (const short*)(base + 192) + quad * 8;
#pragma unroll
    for (int tt = 0; tt < 4; ++tt) {
        int t = tt * 16 + lm;
        if (t < 49) {
            qf[tt] = *(const short8*)(qsrc + (size_t)t * 576);
            kf[tt] = *(const short8*)(ksrc + (size_t)t * 576);
        } else {
            qf[tt] = (short8){0,0,0,0,0,0,0,0};
            kf[tt] = (short8){0,0,0,0,0,0,0,0};
        }
    }

    // ---- S^T = K @ Q^T ----
    const floatx4 z4 = {0.f, 0.f, 0.f, 0.f};
    floatx4 s[4][4];
#pragma unroll
    for (int mt = 0; mt < 4; ++mt)
#pragma unroll
        for (int nt = 0; nt < 4; ++nt)
            s[mt][nt] = __builtin_amdgcn_mfma_f32_16x16x32_bf16(kf[mt], qf[nt], z4, 0, 0, 0);

    // ---- scale + bias/mask/pad table ----
    const float* tb = tbl + (size_t)(head * 4 + cls) * 4096 + lane * 4;
#pragma unroll
    for (int mt = 0; mt < 4; ++mt)
#pragma unroll
        for (int nt = 0; nt < 4; ++nt) {
            floatx4 b = *(const floatx4*)(tb + (mt * 4 + nt) * 256);
#pragma unroll
            for (int rg = 0; rg < 4; ++rg)
                s[mt][nt][rg] = s[mt][nt][rg] * 0.17677669529663689f + b[rg];
        }

    const float gt = 1.0f / (1.0f + __expf(-gate[head]));

    // ---- softmax over k ----
    float inv[4];
#pragma unroll
    for (int nt = 0; nt < 4; ++nt) {
        float mx = -1e30f;
#pragma unroll
        for (int mt = 0; mt < 4; ++mt)
#pragma unroll
            for (int rg = 0; rg < 4; ++rg) mx = fmaxf(mx, s[mt][nt][rg]);
        mx = fmaxf(mx, __shfl_xor(mx, 16));
        mx = fmaxf(mx, __shfl_xor(mx, 32));
        float sum = 0.f;
#pragma unroll
        for (int mt = 0; mt < 4; ++mt)
#pragma unroll
            for (int rg = 0; rg < 4; ++rg) {
                float e = __expf(s[mt][nt][rg] - mx);
                s[mt][nt][rg] = e;
                sum += e;
            }
        sum += __shfl_xor(sum, 16);
        sum += __shfl_xor(sum, 32);
        inv[nt] = gt / sum;
    }

    // ---- pack P -> bf16, swizzled LDS ----
#pragma unroll
    for (int nt = 0; nt < 4; ++nt) {
        int row = nt * 16 + lm;
#pragma unroll
        for (int mt = 0; mt < 4; ++mt) {
            short4v pk = { f2bs(s[mt][nt][0] * inv[nt]), f2bs(s[mt][nt][1] * inv[nt]),
                           f2bs(s[mt][nt][2] * inv[nt]), f2bs(s[mt][nt][3] * inv[nt]) };
            int off = (row * 128 + mt * 32 + quad * 8) ^ ((row & 7) << 4);
            *(short4v*)(Pb + off) = pk;
        }
    }

    // ---- O = P @ V ----
    floatx4 oacc[4][2];
#pragma unroll
    for (int pt = 0; pt < 4; ++pt)
#pragma unroll
        for (int nt = 0; nt < 2; ++nt) oacc[pt][nt] = z4;

#pragma unroll
    for (int ks = 0; ks < 2; ++ks) {
        short8 vfr[2];
#pragma unroll
        for (int nt = 0; nt < 2; ++nt) {
            int row = nt * 16 + lm;
            vfr[nt] = *(const short8*)(vTb + ((row * 128 + ks * 64 + quad * 16) ^ ((row & 7) << 4)));
        }
#pragma unroll
        for (int pt = 0; pt < 4; ++pt) {
            int row = pt * 16 + lm;
            short8 pfr = *(const short8*)(Pb + ((row * 128 + ks * 64 + quad * 16) ^ ((row & 7) << 4)));
#pragma unroll
            for (int nt = 0; nt < 2; ++nt)
                oacc[pt][nt] = __builtin_amdgcn_mfma_f32_16x16x32_bf16(pfr, vfr[nt], oacc[pt][nt], 0, 0, 0);
        }
    }

    // ---- store O ----
    __hip_bfloat16* obase = o + (size_t)win * 49 * 192 + head * 32;
#pragma unroll
    for (int pt = 0; pt < 4; ++pt) {
#pragma unroll
        for (int rg = 0; rg < 4; ++rg) {
            int q = pt * 16 + quad * 4 + rg;
            if (q < 49) {
#pragma unroll
                for (int nt = 0; nt < 2; ++nt)
                    obase[(size_t)q * 192 + nt * 16 + lm] = __float2bfloat16(oacc[pt][nt][rg]);
            }
        }
    }
}

// ---------------------------------------------------------------------------
// MFMA GEMM (qkv MODE 0, proj MODE 1).
// ---------------------------------------------------------------------------
template <int MODE>
__global__ __launch_bounds__(256, 2)
void gemm_bt(const __hip_bfloat16* __restrict__ A,
             const __hip_bfloat16* __restrict__ W,
             const float* __restrict__ bias,
             const float* __restrict__ ex0,
             void* __restrict__ OutV,
             int K, int Ncols)
{
    __shared__ __align__(16) char lds[(128 * 32 + 64 * 32) * 2];  // A: 8KB, B: 4KB
    short* sA = (short*)lds;
    short* sB = (short*)(lds + 8192);

    const int tid  = threadIdx.x;
    const int wave = tid >> 6, lane = tid & 63;
    const int m0 = blockIdx.x * 128;
    const int n0 = blockIdx.y * 64;
    const int wm = wave >> 1, wn = wave & 1;
    const int lm = lane & 15, quad = lane >> 4;

    floatx4 acc[4][2];
#pragma unroll
    for (int mt = 0; mt < 4; ++mt)
#pragma unroll
        for (int nt = 0; nt < 2; ++nt) acc[mt][nt] = (floatx4){0.f, 0.f, 0.f, 0.f};

    for (int kk = 0; kk < K; kk += 32) {
#pragma unroll
        for (int i = 0; i < 2; ++i) {
            int c = i * 256 + tid;
            int row = c >> 2, kc = c & 3;
            const __hip_bfloat16* gp = A + (size_t)(m0 + row) * K + kk + kc * 8;
            char* lp = lds + (i * 256 + wave * 64) * 16;
            __builtin_amdgcn_global_load_lds((const __attribute__((address_space(1))) void*)gp,
                                             (__attribute__((address_space(3))) void*)lp, 16, 0, 0);
        }
        {
            int c = tid;
            int row = c >> 2, kc = c & 3;
            const __hip_bfloat16* gp = W + (size_t)(n0 + row) * K + kk + kc * 8;
            char* lp = lds + 8192 + (wave * 64) * 16;
            __builtin_amdgcn_global_load_lds((const __attribute__((address_space(1))) void*)gp,
                                             (__attribute__((address_space(3))) void*)lp, 16, 0, 0);
        }
        asm volatile("s_waitcnt vmcnt(0)" ::: "memory");
        __syncthreads();

        short8 af[4], bf[2];
#pragma unroll
        for (int mt = 0; mt < 4; ++mt)
            af[mt] = *(const short8*)(sA + ((wm * 64 + mt * 16 + lm) * 32 + quad * 8));
#pragma unroll
        for (int nt = 0; nt < 2; ++nt)
            bf[nt] = *(const short8*)(sB + ((wn * 32 + nt * 16 + lm) * 32 + quad * 8));
#pragma unroll
        for (int mt = 0; mt < 4; ++mt)
#pragma unroll
            for (int nt = 0; nt < 2; ++nt)
                acc[mt][nt] = __builtin_amdgcn_mfma_f32_16x16x32_bf16(af[mt], bf[nt], acc[mt][nt], 0, 0, 0);
        __syncthreads();
    }

#pragma unroll
    for (int mt = 0; mt < 4; ++mt) {
#pragma unroll
        for (int nt = 0; nt < 2; ++nt) {
            int col = n0 + wn * 32 + nt * 16 + lm;
            float bcol = bias[col];
#pragma unroll
            for (int rg = 0; rg < 4; ++rg) {
                int row = m0 + wm * 64 + mt * 16 + quad * 4 + rg;
                float val = acc[mt][nt][rg] + bcol;
                if (MODE == 0) {
                    ((__hip_bfloat16*)OutV)[(size_t)row * Ncols + col] = __float2bfloat16(val);
                } else {  // MODE 1: proj + window reverse + unshift + residual
                    int win = row / 49, t = row - win * 49;
                    int b = win >> 6, wi = win & 63;
                    int wh = wi >> 3, ww = wi & 7;
                    int tr = t / 7, tc = t - tr * 7;
                    int h = wh * 7 + tr + 3; if (h >= 56) h -= 56;
                    int w = ww * 7 + tc + 3; if (w >= 56) w -= 56;
                    size_t dst = ((size_t)b * 3136 + h * 56 + w) * 192 + col;
                    ((float*)OutV)[dst] = val + ex0[dst];
                }
            }
        }
    }
}

// ---------------------------------------------------------------------------
// Fused MLP v3.1: barrier-light, register-resident.
// IDENTICAL to v3 except phase B is FULLY unrolled: the round-4 version used
// `#pragma unroll 4` which left `ct` runtime -> acc[mt][ct] dynamically
// indexed -> the whole accumulator allocated in SCRATCH (VGPR_Count=88,
// 5.9 GB HBM of spill traffic, 1304 us). All acc/zf/aa/hf indexing is now
// compile-time-constant so state stays in registers.
// ---------------------------------------------------------------------------
__global__ __launch_bounds__(256, 2)
void mlp_fused(float* __restrict__ xio,
               const __hip_bfloat16* __restrict__ w1f,
               const __hip_bfloat16* __restrict__ w2f,
               const float* __restrict__ fc1_b,
               const float* __restrict__ bn_g,
               const float* __restrict__ bn_b,
               const float* __restrict__ fc2_b,
               const float* __restrict__ n2g,
               const float* __restrict__ n2b)
{
    __shared__ __align__(16) char wlds[2][24576];   // per buf: w1 slab 12KB + w2 slab 12KB

    const int tid = threadIdx.x;
    const int wave = tid >> 6, lane = tid & 63;
    const int lm = lane & 15, quad = lane >> 4;
    const int t0 = blockIdx.x * 128 + wave * 32;

    // ---- phase 0: LN2 of this wave's 32 tokens -> z fragments in regs ----
    // zf[mt][ks]: lane (lm,quad) holds z[t0+mt*16+lm][ks*32+quad*8 .. +7]
    short8 zf[2][6];
    {
        floatx4 gg[6][2], bb[6][2];
#pragma unroll
        for (int ks = 0; ks < 6; ++ks) {
            gg[ks][0] = *(const floatx4*)(n2g + ks * 32 + quad * 8);
            gg[ks][1] = *(const floatx4*)(n2g + ks * 32 + quad * 8 + 4);
            bb[ks][0] = *(const floatx4*)(n2b + ks * 32 + quad * 8);
            bb[ks][1] = *(const floatx4*)(n2b + ks * 32 + quad * 8 + 4);
        }
#pragma unroll
        for (int mt = 0; mt < 2; ++mt) {
            const float* src = xio + (size_t)(t0 + mt * 16 + lm) * 192 + quad * 8;
            floatx4 v[6][2];
#pragma unroll
            for (int ks = 0; ks < 6; ++ks) {
                v[ks][0] = *(const floatx4*)(src + ks * 32);
                v[ks][1] = *(const floatx4*)(src + ks * 32 + 4);
            }
            float s = 0.f, s2 = 0.f;
#pragma unroll
            for (int ks = 0; ks < 6; ++ks)
#pragma unroll
                for (int h = 0; h < 2; ++h)
#pragma unroll
                    for (int r = 0; r < 4; ++r) { float x = v[ks][h][r]; s += x; s2 += x * x; }
            s  += __shfl_xor(s, 16);  s  += __shfl_xor(s, 32);
            s2 += __shfl_xor(s2, 16); s2 += __shfl_xor(s2, 32);
            float mean = s * (1.0f / 192.0f);
            float var  = s2 * (1.0f / 192.0f) - mean * mean;
            float rstd = rsqrtf(var + 1e-5f);
#pragma unroll
            for (int ks = 0; ks < 6; ++ks)
#pragma unroll
                for (int h = 0; h < 2; ++h)
#pragma unroll
                    for (int r = 0; r < 4; ++r) {
                        float nv = (v[ks][h][r] - mean) * rstd * gg[ks][h][r] + bb[ks][h][r];
                        zf[mt][ks][h * 4 + r] = f2bs(nv);
                    }
        }
    }

    floatx4 acc[2][12];
#pragma unroll
    for (int mt = 0; mt < 2; ++mt)
#pragma unroll
        for (int ct = 0; ct < 12; ++ct) acc[mt][ct] = (floatx4){0.f, 0.f, 0.f, 0.f};

    // ---- weight staging: kg slab = w1f[kg*12KB] (12KB) + w2f[kg*12KB] (12KB) ----
    auto stage = [&](int kg, int p) {
        const char* g1 = (const char*)w1f + (size_t)kg * 12288 + wave * 1024 + lane * 16;
        const char* g2 = (const char*)w2f + (size_t)kg * 12288 + wave * 1024 + lane * 16;
        char* l1 = &wlds[p][0] + wave * 1024;
        char* l2 = &wlds[p][0] + 12288 + wave * 1024;
#pragma unroll
        for (int i = 0; i < 3; ++i) {
            __builtin_amdgcn_global_load_lds((const __attribute__((address_space(1))) void*)(g1 + i * 4096),
                                             (__attribute__((address_space(3))) void*)(l1 + i * 4096), 16, 0, 0);
            __builtin_amdgcn_global_load_lds((const __attribute__((address_space(1))) void*)(g2 + i * 4096),
                                             (__attribute__((address_space(3))) void*)(l2 + i * 4096), 16, 0, 0);
        }
    };

    stage(0, 0);
    asm volatile("s_waitcnt vmcnt(0)" ::: "memory");
    __syncthreads();

    const int srcA = (quad & 1) * 32 + lm;
    const int srcB = srcA + 16;
    const int hi = quad >> 1;   // which h-col tile this lane's phase-B fragment needs

    int cur = 0;
    for (int kg = 0; kg < 24; ++kg) {
        if (kg < 23) stage(kg + 1, cur ^ 1);
        const char* sw1 = &wlds[cur][0];
        const char* sw2 = &wlds[cur][0] + 12288;

        // ---- phase A: aa[mt][u], token=t0+mt*16+lm, hcol=kg*32+u*16+quad*4+rg ----
        floatx4 aa[2][2];
#pragma unroll
        for (int mt = 0; mt < 2; ++mt)
#pragma unroll
            for (int u = 0; u < 2; ++u) aa[mt][u] = (floatx4){0.f, 0.f, 0.f, 0.f};
#pragma unroll
        for (int ks = 0; ks < 6; ++ks) {
            short8 wf0 = *(const short8*)(sw1 + ks * 1024 + lane * 16);
            short8 wf1 = *(const short8*)(sw1 + 6144 + ks * 1024 + lane * 16);
#pragma unroll
            for (int mt = 0; mt < 2; ++mt) {
                aa[mt][0] = __builtin_amdgcn_mfma_f32_16x16x32_bf16(wf0, zf[mt][ks], aa[mt][0], 0, 0, 0);
                aa[mt][1] = __builtin_amdgcn_mfma_f32_16x16x32_bf16(wf1, zf[mt][ks], aa[mt][1], 0, 0, 0);
            }
        }

        // ---- BN + GELU + pack; pw[mt][u][w] = packed bf16 pair (rg=2w, 2w+1) ----
        int pw[2][2][2];
#pragma unroll
        for (int u = 0; u < 2; ++u) {
            int colb = kg * 32 + u * 16 + quad * 4;
            floatx4 fb = *(const floatx4*)(fc1_b + colb);
            floatx4 G  = *(const floatx4*)(bn_g + colb);
            floatx4 Bb = *(const floatx4*)(bn_b + colb);
#pragma unroll
            for (int mt = 0; mt < 2; ++mt) {
                short hs[4];
#pragma unroll
                for (int rg = 0; rg < 4; ++rg) {
                    float t2 = (aa[mt][u][rg] + fb[rg]) * (G[rg] * 0.99999500003749968f) + Bb[rg];
                    float ge = 0.5f * t2 * (1.0f + erff(t2 * 0.70710678118654752f));
                    hs[rg] = f2bs(ge);
                }
                pw[mt][u][0] = (int)(unsigned short)hs[0] | ((int)(unsigned short)hs[1] << 16);
                pw[mt][u][1] = (int)(unsigned short)hs[2] | ((int)(unsigned short)hs[3] << 16);
            }
        }

        // ---- shfl-relayout into phase-B A-operand fragments ----
        // dest lane (lm,q) word i <- src lane (q&1)*32+lm + (i>>1)*16, word i&1, tile q>>1
        short8 hf[2];
#pragma unroll
        for (int mt = 0; mt < 2; ++mt) {
            int a0 = __shfl(pw[mt][0][0], srcA), a1 = __shfl(pw[mt][0][1], srcA);
            int a2 = __shfl(pw[mt][0][0], srcB), a3 = __shfl(pw[mt][0][1], srcB);
            int b0 = __shfl(pw[mt][1][0], srcA), b1 = __shfl(pw[mt][1][1], srcA);
            int b2 = __shfl(pw[mt][1][0], srcB), b3 = __shfl(pw[mt][1][1], srcB);
            union { int i[4]; short8 s; } u4;
            u4.i[0] = hi ? b0 : a0;
            u4.i[1] = hi ? b1 : a1;
            u4.i[2] = hi ? b2 : a2;
            u4.i[3] = hi ? b3 : a3;
            hf[mt] = u4.s;
        }

        // ---- phase B: acc[mt][ct] += hf[mt] @ w2[ct-tile, kg] ----
        // FULL unroll: ct must be compile-time so acc stays in registers.
#pragma unroll
        for (int ct = 0; ct < 12; ++ct) {
            short8 vf = *(const short8*)(sw2 + ct * 1024 + lane * 16);
            acc[0][ct] = __builtin_amdgcn_mfma_f32_16x16x32_bf16(hf[0], vf, acc[0][ct], 0, 0, 0);
            acc[1][ct] = __builtin_amdgcn_mfma_f32_16x16x32_bf16(hf[1], vf, acc[1][ct], 0, 0, 0);
        }

        asm volatile("s_waitcnt vmcnt(0)" ::: "memory");
        __syncthreads();
        cur ^= 1;
    }

    // ---- epilogue: + fc2_b + x1 residual, fp32 store in place ----
    // acc: out-col = ct*16+lm, token = t0 + mt*16 + quad*4 + rg
#pragma unroll
    for (int ct = 0; ct < 12; ++ct) {
        float fb = fc2_b[ct * 16 + lm];
#pragma unroll
        for (int mt = 0; mt < 2; ++mt) {
#pragma unroll
            for (int rg = 0; rg < 4; ++rg) {
                size_t dst = (size_t)(t0 + mt * 16 + quad * 4 + rg) * 192 + ct * 16 + lm;
                xio[dst] = acc[mt][ct][rg] + fb + xio[dst];
            }
        }
    }
}

// ---------------------------------------------------------------------------
extern "C" void kernel_launch(void* const* d_in, const int* in_sizes, int n_in,
                              void* d_out, int out_size, void* d_ws, size_t ws_size,
                              hipStream_t stream)
{
    const float* x      = (const float*)d_in[0];
    const float* n1g    = (const float*)d_in[1];
    const float* n1b    = (const float*)d_in[2];
    const float* qkv_w  = (const float*)d_in[3];
    const float* qkv_b  = (const float*)d_in[4];
    const float* rpb    = (const float*)d_in[5];
    const float* gate   = (const float*)d_in[6];
    const float* proj_w = (const float*)d_in[7];
    const float* proj_b = (const float*)d_in[8];
    const float* n2g    = (const float*)d_in[9];
    const float* n2b    = (const float*)d_in[10];
    const float* fc1_w  = (const float*)d_in[11];
    const float* fc1_b  = (const float*)d_in[12];
    const float* bn_g   = (const float*)d_in[13];
    const float* bn_b   = (const float*)d_in[14];
    const float* fc2_w  = (const float*)d_in[15];
    const float* fc2_b  = (const float*)d_in[16];
    float* out = (float*)d_out;

    char* ws = (char*)d_ws;
    const int NCH = (ws_size >= 155025408u) ? 4 : 8;
    const size_t buf1max = (NCH == 4) ? 77070336u : 38535168u;
    __hip_bfloat16* buf0 = (__hip_bfloat16*)(ws);
    __hip_bfloat16* buf1 = (__hip_bfloat16*)(ws + 77070336);
    __hip_bfloat16* wbuf = (__hip_bfloat16*)(ws + 77070336 + buf1max);
    __hip_bfloat16* wq  = wbuf;            // 110592 (row-major)
    __hip_bfloat16* wp  = wbuf + 110592;   // 36864  (row-major)
    __hip_bfloat16* w1f = wbuf + 147456;   // 147456 (fragment layout, per-kg slabs)
    __hip_bfloat16* w2f = wbuf + 294912;   // 147456 (fragment layout, per-kg slabs)

    const int WINS = 4096 / NCH;        // windows per chunk (multiple of 64)
    const int ROWS = WINS * 49;         // rows per chunk
    const int GX   = ROWS / 128;        // gemm grid.x per chunk

    // attention bias table lives in buf1 AFTER the per-chunk qkv region.
    float* tbl = (float*)(ws + 77070336 + (size_t)ROWS * 576 * 2);

    // 0. Weights fp32 -> bf16 (w1/w2 into per-kg fragment slabs); bias+mask table
    cvt_w<<<dim3(1728), 256, 0, stream>>>(qkv_w, proj_w, fc1_w, fc2_w, wbuf);
    build_tbl<<<dim3(24), 256, 0, stream>>>(rpb, tbl);

    // 1. LN1 + shift + window partition (all rows)
    ln1_shift_win<<<dim3(200704 / 4), 256, 0, stream>>>(x, n1g, n1b, buf0);

    // 2+3. Per chunk: QKV gemm then MFMA attention
    for (int c = 0; c < NCH; ++c) {
        const __hip_bfloat16* ywc = buf0 + (size_t)c * ROWS * 192;
        __hip_bfloat16*       oc  = buf0 + (size_t)c * ROWS * 192;
        gemm_bt<0><<<dim3(GX, 9), 256, 0, stream>>>(ywc, wq, qkv_b, nullptr, buf1, 192, 576);
        attn_mfma<<<dim3(WINS * 6 / 4), 256, 0, stream>>>(buf1, tbl, gate, oc);
    }

    // 4. proj gemm + window reverse + unshift + shortcut -> x1 (fp32) in d_out
    gemm_bt<1><<<dim3(1568, 3), 256, 0, stream>>>(buf0, wp, proj_b, x, out, 192, 192);

    // 5. Fused LN2 + FC1 + BN + GELU + FC2 + residual (in-place on d_out)
    mlp_fused<<<dim3(1568), 256, 0, stream>>>(out, w1f, w2f, fc1_b, bn_g, bn_b, fc2_b, n2g, n2b);
}